// Round 1
// baseline (107.172 us; speedup 1.0000x reference)
//
#include <hip/hip_runtime.h>
#include <math.h>

// Chamfer loss, B=32 batches, N=2048 points each side, 3 used components.
// p: (2,32,2048,4) fp32 -- only p[0] used; q: (32,2048,4) fp32.
// loss = sum_b,n 0.5*min_m dist + sum_b,m 0.5*min_n dist,
// dist = sqrt(max(d2,0)+1e-16). sqrt is monotone -> min over d2 first.
// d2(n,m) = x2[n] + (y2[m] - 2*dot(p_n, q_m)); x2 const per thread, so we
// only track gmin = min_m (y2[m] - 2*dot) -> 4 VALU/pair + min3 amortized.

#define NPTS 2048
#define NBATCH 32
#define EPSF 1e-16f

__device__ __forceinline__ float min3f(float a, float b, float c) {
    return fminf(fminf(a, b), c);   // -> v_min3_f32
}

__global__ __launch_bounds__(256, 2) void chamfer_kernel(
    const float* __restrict__ P, const float* __restrict__ Q,
    float* __restrict__ out)
{
    __shared__ float sx[NPTS], sy[NPTS], sz[NPTS], s2[NPTS];  // 32 KB
    __shared__ float rbuf[4];

    const int tid   = threadIdx.x;
    const int chunk = blockIdx.x;   // 0..7 -> which 256 "own" points
    const int b     = blockIdx.y;   // 0..31 batch
    const int dir   = blockIdx.z;   // 0: own P / stage Q ; 1: own Q / stage P

    const float* own   = dir ? Q : P;
    const float* other = dir ? P : Q;

    // ---- stage `other[b]` into LDS as SoA + squared norm (float4 coalesced)
    const float4* o4 = (const float4*)(other + (size_t)b * NPTS * 4);
    for (int m = tid; m < NPTS; m += 256) {
        float4 v = o4[m];           // v.x is the discarded component 0
        sx[m] = v.y; sy[m] = v.z; sz[m] = v.w;
        s2[m] = v.y * v.y + v.z * v.z + v.w * v.w;
    }
    __syncthreads();

    // ---- own point
    const int n = chunk * 256 + tid;
    float4 pv = ((const float4*)(own + (size_t)b * NPTS * 4))[n];
    const float px = pv.y, py = pv.z, pz = pv.w;
    const float x2 = px * px + py * py + pz * pz;

    // ---- main loop: min_m ( s2[m] - 2*dot )
    float acc0 = 3.4e38f, acc1 = 3.4e38f;
    for (int m = 0; m < NPTS; m += 4) {
        float4 xs = *(const float4*)&sx[m];   // ds_read_b128, uniform broadcast
        float4 ys = *(const float4*)&sy[m];
        float4 zs = *(const float4*)&sz[m];
        float4 n2 = *(const float4*)&s2[m];
        float d0 = px * xs.x + py * ys.x + pz * zs.x;
        float d1 = px * xs.y + py * ys.y + pz * zs.y;
        float d2 = px * xs.z + py * ys.z + pz * zs.z;
        float d3 = px * xs.w + py * ys.w + pz * zs.w;
        float g0 = fmaf(-2.f, d0, n2.x);
        float g1 = fmaf(-2.f, d1, n2.y);
        float g2 = fmaf(-2.f, d2, n2.z);
        float g3 = fmaf(-2.f, d3, n2.w);
        acc0 = min3f(acc0, g0, g1);
        acc1 = min3f(acc1, g2, g3);
    }
    const float gmin  = fminf(acc0, acc1);
    const float dmin2 = x2 + gmin;
    const float dist  = sqrtf(fmaxf(dmin2, 0.f) + EPSF);

    // ---- block sum of dist, one atomic per block
    float v = dist;
    #pragma unroll
    for (int off = 32; off > 0; off >>= 1) v += __shfl_down(v, off);
    if ((tid & 63) == 0) rbuf[tid >> 6] = v;
    __syncthreads();
    if (tid == 0) {
        float s = (rbuf[0] + rbuf[1]) + (rbuf[2] + rbuf[3]);
        atomicAdd(out, 0.5f * s);
    }
}

extern "C" void kernel_launch(void* const* d_in, const int* in_sizes, int n_in,
                              void* d_out, int out_size, void* d_ws, size_t ws_size,
                              hipStream_t stream) {
    const float* P = (const float*)d_in[0];  // p[0] is the first 32*2048*4 floats
    const float* Q = (const float*)d_in[1];
    float* out = (float*)d_out;

    hipMemsetAsync(out, 0, sizeof(float), stream);  // capture-safe
    dim3 grid(NPTS / 256, NBATCH, 2);               // 8 x 32 x 2 = 512 blocks
    chamfer_kernel<<<grid, 256, 0, stream>>>(P, Q, out);
}

// Round 2
// 95.814 us; speedup vs baseline: 1.1185x; 1.1185x over previous
//
#include <hip/hip_runtime.h>
#include <math.h>

// Chamfer loss, B=32, N=2048, 3 used components of inner dim-4.
// Strategy (R1): min over SQUARED metric g = |q|^2 - 2*dot (x2 added later),
// AoS LDS staging {y,z,w,|q|^2} -> 1 broadcast ds_read_b128 per staged point,
// 4 own points per thread (register tiling) -> 18 VALU per 1 LDS read,
// m-dim split 8-way for occupancy; partial minima combined via atomicMin on
// uint-cast nonneg floats in d_ws; second kernel sums 0.5*sqrt(min+eps).

#define NPTS   2048
#define NBATCH 32
#define NTOT   (2 * NBATCH * NPTS)   // 131072 own points total
#define MCHUNK 256                   // staged m-points per block
#define EPSF   1e-16f

__device__ __forceinline__ float min3f(float a, float b, float c) {
    return fminf(fminf(a, b), c);    // -> v_min3_f32
}

__global__ __launch_bounds__(256, 4) void chamfer_min_kernel(
    const float* __restrict__ P, const float* __restrict__ Q,
    unsigned int* __restrict__ ws)
{
    __shared__ float4 sm[MCHUNK];    // {y, z, w, |q|^2}  -- 4 KB

    const int tid      = threadIdx.x;
    const int ownchunk = blockIdx.x;        // 0..1  (1024 own points each)
    const int b        = blockIdx.y;        // 0..31
    const int z        = blockIdx.z;        // 0..15
    const int dir      = z >> 3;            // 0: own P / stage Q ; 1: reverse
    const int mchunk   = z & 7;             // which 256 staged points

    const float* own   = dir ? Q : P;
    const float* other = dir ? P : Q;

    // ---- stage m-chunk as AoS float4 (one coalesced load per thread)
    {
        const float4* o4 = (const float4*)(other + (size_t)b * NPTS * 4)
                         + mchunk * MCHUNK;
        float4 v = o4[tid];
        sm[tid] = make_float4(v.y, v.z, v.w,
                              v.y * v.y + v.z * v.z + v.w * v.w);
    }

    // ---- load 4 own points (coalesced: stride-256 within chunk)
    const float4* w4 = (const float4*)(own + (size_t)b * NPTS * 4)
                     + ownchunk * 1024;
    float px[4], py[4], pz[4], x2v[4];
    #pragma unroll
    for (int k = 0; k < 4; ++k) {
        float4 p = w4[k * 256 + tid];
        px[k] = p.y; py[k] = p.z; pz[k] = p.w;
        x2v[k] = p.y * p.y + p.z * p.z + p.w * p.w;
    }

    __syncthreads();

    // ---- main loop: acc[k] = min_m ( |q_m|^2 - 2*dot(p_k, q_m) )
    float acc[4] = {3.4e38f, 3.4e38f, 3.4e38f, 3.4e38f};
    for (int m = 0; m < MCHUNK; m += 2) {
        float4 q0 = sm[m];       // uniform address -> broadcast, conflict-free
        float4 q1 = sm[m + 1];
        #pragma unroll
        for (int k = 0; k < 4; ++k) {
            float d0 = px[k] * q0.x + py[k] * q0.y + pz[k] * q0.z;
            float d1 = px[k] * q1.x + py[k] * q1.y + pz[k] * q1.z;
            float g0 = fmaf(-2.f, d0, q0.w);
            float g1 = fmaf(-2.f, d1, q1.w);
            acc[k] = min3f(acc[k], g0, g1);
        }
    }

    // ---- publish partial minima: clamp to >=0 (monotone), uint atomicMin
    const int base = dir * (NBATCH * NPTS) + b * NPTS + ownchunk * 1024;
    #pragma unroll
    for (int k = 0; k < 4; ++k) {
        float r = fmaxf(x2v[k] + acc[k], 0.f);          // nonneg
        atomicMin(&ws[base + k * 256 + tid], __float_as_uint(r));
    }
}

__global__ __launch_bounds__(256) void chamfer_sum_kernel(
    const unsigned int* __restrict__ ws, float* __restrict__ out)
{
    __shared__ float rbuf[4];
    const int tid = threadIdx.x;
    const int i0  = blockIdx.x * 256 + tid;

    float s = 0.f;
    for (int i = i0; i < NTOT; i += gridDim.x * 256)
        s += sqrtf(__uint_as_float(ws[i]) + EPSF);

    #pragma unroll
    for (int off = 32; off > 0; off >>= 1) s += __shfl_down(s, off);
    if ((tid & 63) == 0) rbuf[tid >> 6] = s;
    __syncthreads();
    if (tid == 0) {
        atomicAdd(out, 0.5f * ((rbuf[0] + rbuf[1]) + (rbuf[2] + rbuf[3])));
    }
}

extern "C" void kernel_launch(void* const* d_in, const int* in_sizes, int n_in,
                              void* d_out, int out_size, void* d_ws, size_t ws_size,
                              hipStream_t stream) {
    const float* P = (const float*)d_in[0];   // p[0] = first 32*2048*4 floats
    const float* Q = (const float*)d_in[1];
    float* out = (float*)d_out;
    unsigned int* ws = (unsigned int*)d_ws;

    // sentinel 0x7F7F7F7F = 3.39e38f (> any real min; uint-monotone)
    hipMemsetAsync(ws, 0x7F, (size_t)NTOT * sizeof(unsigned int), stream);
    hipMemsetAsync(out, 0, sizeof(float), stream);

    dim3 grid1(2, NBATCH, 16);                 // 2 own-chunks x 32 b x (2 dir * 8 m-chunks)
    chamfer_min_kernel<<<grid1, 256, 0, stream>>>(P, Q, ws);

    chamfer_sum_kernel<<<128, 256, 0, stream>>>(ws, out);
}

// Round 3
// 84.222 us; speedup vs baseline: 1.2725x; 1.1376x over previous
//
#include <hip/hip_runtime.h>
#include <math.h>

// Chamfer loss, B=32, N=2048, 3 used components.
// R2: SYMMETRY -- the q->p dot matrix is the transpose of p->q, so compute
// each pair once and track BOTH row-min (over m, for min_pq) and col-min
// (over n, for min_qp). Staged q' = {-2x,-2y,-2z,|q|^2}, p = {x,y,z,|p|^2}:
//   dot' = p . q'(xyz) ; row tracks min(dot' + y2) ; col tracks min(dot' + x2)
// 6 VALU/pair (3 dot + 2 add + 1 amortized min3). 256x256 tile per block,
// 16x16 register subtile per thread. Partial minima -> global atomicMin on
// uint-cast clamped d2 in ws; sum kernel does 0.5*sum sqrt(min+eps).

#define NPTS   2048
#define NBATCH 32
#define NTOT   (2 * NBATCH * NPTS)   // 131072 min slots
#define EPSF   1e-16f
#define BIGF   3.4e38f

__device__ __forceinline__ float min3f(float a, float b, float c) {
    return fminf(fminf(a, b), c);    // -> v_min3_f32
}

__global__ __launch_bounds__(256) void chamfer_tile_kernel(
    const float* __restrict__ P, const float* __restrict__ Q,
    unsigned int* __restrict__ ws)
{
    __shared__ float4 sp[256];        // {x, y, z, |p|^2}
    __shared__ float4 sq[256];        // {-2x, -2y, -2z, |q|^2}
    __shared__ float  scol[4][256];   // per-wave col partials

    const int tid = threadIdx.x;
    const int tx  = tid & 15;         // col group
    const int ty  = tid >> 4;         // row group (0..15, spans 4 waves)
    const int bi  = blockIdx.x;       // row chunk (p)
    const int bj  = blockIdx.y;       // col chunk (q)
    const int b   = blockIdx.z;       // batch

    // ---- stage tile points (1 float4 load each, coalesced)
    {
        float4 pv = ((const float4*)P)[(size_t)b * NPTS + bi * 256 + tid];
        sp[tid] = make_float4(pv.y, pv.z, pv.w,
                              pv.y*pv.y + pv.z*pv.z + pv.w*pv.w);
        float4 qv = ((const float4*)Q)[(size_t)b * NPTS + bj * 256 + tid];
        sq[tid] = make_float4(-2.f*qv.y, -2.f*qv.z, -2.f*qv.w,
                              qv.y*qv.y + qv.z*qv.z + qv.w*qv.w);
    }
    __syncthreads();

    // ---- thread's 16 p rows: r = ty + 16k (broadcast reads, conflict-free)
    float px[16], py[16], pz[16], x2[16];
    #pragma unroll
    for (int k = 0; k < 16; ++k) {
        float4 v = sp[ty + 16 * k];
        px[k] = v.x; py[k] = v.y; pz[k] = v.z; x2[k] = v.w;
    }

    float rowacc[16], colacc[16];
    #pragma unroll
    for (int k = 0; k < 16; ++k) { rowacc[k] = BIGF; colacc[k] = BIGF; }

    // ---- main loop: j-pairs over thread's 16 cols c = tx + 16j
    for (int jp = 0; jp < 8; ++jp) {
        float4 q0 = sq[tx + 32 * jp];        // j0 = 2*jp
        float4 q1 = sq[tx + 32 * jp + 16];   // j1 = 2*jp+1
        float c0 = BIGF, c1 = BIGF;
        #pragma unroll
        for (int k = 0; k < 16; k += 2) {
            float t00 = fmaf(px[k],   q0.x, fmaf(py[k],   q0.y, pz[k]   * q0.z));
            float t01 = fmaf(px[k],   q1.x, fmaf(py[k],   q1.y, pz[k]   * q1.z));
            float t10 = fmaf(px[k+1], q0.x, fmaf(py[k+1], q0.y, pz[k+1] * q0.z));
            float t11 = fmaf(px[k+1], q1.x, fmaf(py[k+1], q1.y, pz[k+1] * q1.z));
            // row: min over m of (dot' + y2)
            rowacc[k]   = min3f(rowacc[k],   t00 + q0.w, t01 + q1.w);
            rowacc[k+1] = min3f(rowacc[k+1], t10 + q0.w, t11 + q1.w);
            // col: min over n of (dot' + x2)
            c0 = min3f(c0, t00 + x2[k], t10 + x2[k+1]);
            c1 = min3f(c1, t01 + x2[k], t11 + x2[k+1]);
        }
        colacc[2*jp]     = c0;
        colacc[2*jp + 1] = c1;
    }

    // ---- row epilogue: reduce across tx (lane bits 0..3), publish
    #pragma unroll
    for (int k = 0; k < 16; ++k) {
        float v = rowacc[k];
        v = fminf(v, __shfl_xor(v, 1));
        v = fminf(v, __shfl_xor(v, 2));
        v = fminf(v, __shfl_xor(v, 4));
        v = fminf(v, __shfl_xor(v, 8));
        rowacc[k] = v;
    }
    if (tx == 0) {
        #pragma unroll
        for (int k = 0; k < 16; ++k) {
            float d2 = fmaxf(x2[k] + rowacc[k], 0.f);
            atomicMin(&ws[b * NPTS + bi * 256 + (ty + 16 * k)],
                      __float_as_uint(d2));
        }
    }

    // ---- col epilogue: reduce across ty. In-wave: lane bits 4,5.
    #pragma unroll
    for (int j = 0; j < 16; ++j) {
        float v = colacc[j];
        v = fminf(v, __shfl_xor(v, 16));
        v = fminf(v, __shfl_xor(v, 32));
        colacc[j] = v;
    }
    {
        const int wv   = tid >> 6;
        const int lane = tid & 63;
        if (lane < 16) {               // lane == tx, w_ty == 0
            #pragma unroll
            for (int j = 0; j < 16; ++j) scol[wv][j * 16 + lane] = colacc[j];
        }
    }
    __syncthreads();
    {
        const int c = tid;             // col index in tile; scol idx == c
        float v = fminf(fminf(scol[0][c], scol[1][c]),
                        fminf(scol[2][c], scol[3][c]));
        float d2 = fmaxf(v + sq[c].w, 0.f);
        atomicMin(&ws[NBATCH * NPTS + b * NPTS + bj * 256 + c],
                  __float_as_uint(d2));
    }
}

__global__ __launch_bounds__(256) void chamfer_sum_kernel(
    const unsigned int* __restrict__ ws, float* __restrict__ out)
{
    __shared__ float rbuf[4];
    const int tid = threadIdx.x;
    const int i0  = blockIdx.x * 256 + tid;

    float s = 0.f;
    for (int i = i0; i < NTOT; i += gridDim.x * 256)
        s += sqrtf(__uint_as_float(ws[i]) + EPSF);

    #pragma unroll
    for (int off = 32; off > 0; off >>= 1) s += __shfl_down(s, off);
    if ((tid & 63) == 0) rbuf[tid >> 6] = s;
    __syncthreads();
    if (tid == 0)
        atomicAdd(out, 0.5f * ((rbuf[0] + rbuf[1]) + (rbuf[2] + rbuf[3])));
}

extern "C" void kernel_launch(void* const* d_in, const int* in_sizes, int n_in,
                              void* d_out, int out_size, void* d_ws, size_t ws_size,
                              hipStream_t stream) {
    const float* P = (const float*)d_in[0];   // p[0] = first 32*2048*4 floats
    const float* Q = (const float*)d_in[1];
    float* out = (float*)d_out;
    unsigned int* ws = (unsigned int*)d_ws;

    // sentinel 0x7F7F7F7F = 3.39e38f (uint-monotone for nonneg floats)
    hipMemsetAsync(ws, 0x7F, (size_t)NTOT * sizeof(unsigned int), stream);
    hipMemsetAsync(out, 0, sizeof(float), stream);

    dim3 grid(NPTS / 256, NPTS / 256, NBATCH);   // 8 x 8 x 32 = 2048 blocks
    chamfer_tile_kernel<<<grid, 256, 0, stream>>>(P, Q, ws);

    chamfer_sum_kernel<<<128, 256, 0, stream>>>(ws, out);
}